// Round 2
// baseline (2718.930 us; speedup 1.0000x reference)
//
#include <hip/hip_runtime.h>

#define DIMC 180
#define NHEADS 6
#define NTOK 64
#define NWIN 4096
#define OUT1_ELEMS (NWIN * NTOK * DIMC)  // 47185920 floats per output tensor

typedef _Float16 f16;
typedef _Float16 f16x8 __attribute__((ext_vector_type(8)));
typedef _Float16 f16x4 __attribute__((ext_vector_type(4)));
typedef float    f32x4 __attribute__((ext_vector_type(4)));

// ---- workspace layout (bytes). Total 989184 B (<1 MB).
#define WS_WQKV_E   0         // [576][192] f16  (col-major-transposed, head-padded)
#define WS_WQKV_B   221184
#define WS_WPS_E    442368    // [192][192] f16  (transposed, zero-padded)
#define WS_WPS_B    516096
#define WS_WPE_T    589824    // [192][384] f16  (transposed, K padded 360->384)
#define WS_WPB_T    737280
#define WS_BQKV_E   884736    // [576] f32 (packed head-padded qkv bias)
#define WS_BQKV_B   887040
#define WS_BPS_E    889344    // [192] f32
#define WS_BPS_B    890112
#define WS_BIAS     890880    // [6][64][64] f32 = rpb_table[rpi]
// end: 989184

// MFMA fragment conventions (gfx950 v_mfma_f32_16x16x32_f16, verified set):
//   A-frag: lane l holds A[row = l&15][k = (l>>4)*8 + j], j=0..7  (16B contiguous)
//   B-frag: lane l holds B[k = (l>>4)*8 + j][col = l&15]          (read from W^T)
//   C/D   : lane l, reg r -> row = (l>>4)*4 + r, col = l&15

// ---------------------------------------------------------------------------
// Kernel 0: one-time weight packing (f32 -> f16, pad, transpose) + bias table.
// ---------------------------------------------------------------------------
__global__ __launch_bounds__(256) void pack_kernel(
    const float* __restrict__ Wqkv_e, const float* __restrict__ bqkv_e,
    const float* __restrict__ Wqkv_b, const float* __restrict__ bqkv_b,
    const float* __restrict__ Wpe_s,  const float* __restrict__ bpe_s,
    const float* __restrict__ Wpb_s,  const float* __restrict__ bpb_s,
    const float* __restrict__ Wpe,    const float* __restrict__ Wpb,
    const float* __restrict__ rpb_table, const int* __restrict__ rpi,
    unsigned char* __restrict__ ws)
{
    const int gid  = blockIdx.x * blockDim.x + threadIdx.x;
    const int nthr = gridDim.x * blockDim.x;

    // QKV: packed col c = sec*192 + h*32 + d  (d<30 real, 30/31 zero); k padded to 192.
    f16* wq = (f16*)(ws + WS_WQKV_E);
    for (int idx = gid; idx < 2 * 576 * 192; idx += nthr) {
        int br = idx / (576 * 192), r = idx % (576 * 192);
        int c = r / 192, k = r % 192;
        int s = c / 192, rr = c % 192, h = rr / 32, d = rr % 32;
        const float* W = br ? Wqkv_b : Wqkv_e;
        float v = (d < 30 && k < 180) ? W[k * 540 + s * 180 + h * 30 + d] : 0.f;
        wq[idx] = (f16)v;
    }
    f16* wp = (f16*)(ws + WS_WPS_E);
    for (int idx = gid; idx < 2 * 192 * 192; idx += nthr) {
        int br = idx / (192 * 192), r = idx % (192 * 192);
        int c = r / 192, k = r % 192;
        const float* W = br ? Wpb_s : Wpe_s;
        float v = (c < 180 && k < 180) ? W[k * 180 + c] : 0.f;
        wp[idx] = (f16)v;
    }
    // Final-proj: K layout [oe(180) | 0(12) | ob(180) | 0(12)] = 384, transposed.
    f16* wt = (f16*)(ws + WS_WPE_T);
    for (int idx = gid; idx < 2 * 192 * 384; idx += nthr) {
        int o = idx / (192 * 384), r = idx % (192 * 384);
        int c = r / 384, k = r % 384;
        const float* W = o ? Wpb : Wpe;
        int krow = (k < 180) ? k : ((k >= 192 && k < 372) ? (180 + k - 192) : -1);
        float v = (c < 180 && krow >= 0) ? W[krow * 180 + c] : 0.f;
        wt[idx] = (f16)v;
    }
    float* bq = (float*)(ws + WS_BQKV_E);
    for (int idx = gid; idx < 2 * 576; idx += nthr) {
        int br = idx / 576, c = idx % 576;
        int s = c / 192, rr = c % 192, h = rr / 32, d = rr % 32;
        const float* B = br ? bqkv_b : bqkv_e;
        bq[idx] = (d < 30) ? B[s * 180 + h * 30 + d] : 0.f;
    }
    float* bp = (float*)(ws + WS_BPS_E);
    for (int idx = gid; idx < 2 * 192; idx += nthr) {
        int br = idx / 192, c = idx % 192;
        const float* B = br ? bpb_s : bpe_s;
        bp[idx] = (c < 180) ? B[c] : 0.f;
    }
    float* bh = (float*)(ws + WS_BIAS);
    for (int idx = gid; idx < 6 * 4096; idx += nthr) {
        int h = idx / 4096, ij = idx % 4096;
        bh[idx] = rpb_table[rpi[ij] * NHEADS + h];
    }
}

// ---------------------------------------------------------------------------
// Kernel A: per (window, branch). MFMA sigmoid-gate proj + QKV + attention.
// LDS: sX (25.6 KB) unioned with the per-head buffers (24.1 KB) because sX is
// dead once each wave holds its A-fragments in registers -> 25600 B total
// -> 6 blocks/CU (was 3). One extra barrier pays for 2x occupancy.
// ---------------------------------------------------------------------------
__global__ __launch_bounds__(256, 6) void attn_kernel(
    const float* __restrict__ e, const float* __restrict__ b,
    const float* __restrict__ mask,
    const unsigned char* __restrict__ ws,
    float* __restrict__ d_out)
{
    const int w    = blockIdx.x;
    const int br   = blockIdx.y;
    const int tid  = threadIdx.x;
    const int lane = tid & 63;
    const int l15  = lane & 15;
    const int l4   = lane >> 4;
    const int wid  = __builtin_amdgcn_readfirstlane(tid >> 6);  // 0..3

    // union: phase 1 uses sX [64][200]; phase 2 reuses the same bytes for
    // sQ [64][40] | sK [64][40] | sVt [32][72] | sP [64][72]  (all 16B-aligned)
    __shared__ __align__(16) unsigned char smem[25600];
    f16* sX  = (f16*)smem;
    f16* sQ  = (f16*)smem;                   // 5120 B
    f16* sK  = (f16*)(smem + 5120);          // 5120 B
    f16* sVt = (f16*)(smem + 10240);         // 4608 B
    f16* sP  = (f16*)(smem + 14848);         // 9216 B (ends 24064)

    const float* x   = br ? b : e;
    const f16*   Wq  = (const f16*)(ws + (br ? WS_WQKV_B : WS_WQKV_E));
    const f16*   Wp  = (const f16*)(ws + (br ? WS_WPS_B  : WS_WPS_E));
    const float* bq  = (const float*)(ws + (br ? WS_BQKV_B : WS_BQKV_E));
    const float* bp  = (const float*)(ws + (br ? WS_BPS_B  : WS_BPS_E));
    const float* bh0 = (const float*)(ws + WS_BIAS);

    // ---- stage X (f32 -> f16), zero the K-pad cols 180..199
    const float* xw = x + (size_t)w * (NTOK * DIMC);
    for (int idx = tid; idx < 2880; idx += 256) {           // 64*45 float4
        int row = idx / 45, c4 = (idx % 45) * 4;
        const float4 v = *(const float4*)(xw + row * 180 + c4);
        f16x4 hv = { (f16)v.x, (f16)v.y, (f16)v.z, (f16)v.w };
        *(f16x4*)&sX[row * 200 + c4] = hv;
    }
    for (int idx = tid; idx < 320; idx += 256) {            // 64*5 pad chunks
        int row = idx / 5, c4 = 180 + (idx % 5) * 4;
        *(f16x4*)&sX[row * 200 + c4] = (f16x4){0, 0, 0, 0};
    }
    // mask stays exact f32, preloaded once into regs (this thread's 16 S-entries)
    float mreg[4][4];
    {
        const float* mw = mask + (size_t)w * 4096;
        const int rbase = wid * 16 + l4 * 4;
#pragma unroll
        for (int nt = 0; nt < 4; ++nt)
#pragma unroll
            for (int r = 0; r < 4; ++r)
                mreg[nt][r] = mw[(rbase + r) * 64 + nt * 16 + l15];
    }
    __syncthreads();

    // persistent X A-fragments for this wave's row-block (reused by ALL GEMMs)
    f16x8 a[6];
#pragma unroll
    for (int kk = 0; kk < 6; ++kk)
        a[kk] = *(const f16x8*)&sX[(wid * 16 + l15) * 200 + kk * 32 + l4 * 8];
    __syncthreads();   // sX is dead from here; its bytes become sQ/sK/sVt/sP

    // ---- sigmoid gate projection -> out1-half staging (f16); no LDS use
    f16* sig_stage = (f16*)d_out;
    {
        const size_t base = (size_t)w * 23040 + (size_t)br * 11520;
        for (int nt = 0; nt < 12; ++nt) {
            f32x4 acc = {0, 0, 0, 0};
#pragma unroll
            for (int kk = 0; kk < 6; ++kk) {
                f16x8 bf = *(const f16x8*)&Wp[(size_t)(nt * 16 + l15) * 192 + kk * 32 + l4 * 8];
                acc = __builtin_amdgcn_mfma_f32_16x16x32_f16(a[kk], bf, acc, 0, 0, 0);
            }
            const int col = nt * 16 + l15;
            if (col < 180) {
                const float bv = bp[col];
#pragma unroll
                for (int r = 0; r < 4; ++r) {
                    const int row = wid * 16 + l4 * 4 + r;
                    float s = 1.f / (1.f + __expf(-(acc[r] + bv)));
                    sig_stage[base + row * 180 + col] = (f16)s;
                }
            }
        }
    }

    f16* out_stage = (f16*)(d_out + OUT1_ELEMS);
    const float scale = 0.18257418583505536f;  // 30^-0.5

    for (int h = 0; h < NHEADS; ++h) {
        // ---- QKV projection for head h (wave wid owns token rows wid*16..+15)
#pragma unroll
        for (int sec = 0; sec < 3; ++sec) {
#pragma unroll
            for (int nt = 0; nt < 2; ++nt) {
                const int colp = sec * 192 + h * 32 + nt * 16;
                f32x4 acc = {0, 0, 0, 0};
#pragma unroll
                for (int kk = 0; kk < 6; ++kk) {
                    f16x8 bf = *(const f16x8*)&Wq[(size_t)(colp + l15) * 192 + kk * 32 + l4 * 8];
                    acc = __builtin_amdgcn_mfma_f32_16x16x32_f16(a[kk], bf, acc, 0, 0, 0);
                }
                const float bv = bq[colp + l15];
                const int d = nt * 16 + l15;           // 0..31 within head (30,31 are zero)
                if (sec == 2) {
                    f16x4 vv;
#pragma unroll
                    for (int r = 0; r < 4; ++r) vv[r] = (f16)(acc[r] + bv);
                    *(f16x4*)&sVt[d * 72 + wid * 16 + l4 * 4] = vv;   // V transposed
                } else {
                    f16* dst = sec ? sK : sQ;
#pragma unroll
                    for (int r = 0; r < 4; ++r)
                        dst[(wid * 16 + l4 * 4 + r) * 40 + d] = (f16)(acc[r] + bv);
                }
            }
        }
        __syncthreads();

        // ---- S = scale*Q K^T + bias + mask  (one MFMA per 16x16 tile, K=32)
        const float* bh = bh0 + h * 4096;
        const f16x8 qa = *(const f16x8*)&sQ[(wid * 16 + l15) * 40 + l4 * 8];
        float sc[4][4];
#pragma unroll
        for (int nt = 0; nt < 4; ++nt) {
            f16x8 kb = *(const f16x8*)&sK[(nt * 16 + l15) * 40 + l4 * 8];
            f32x4 s4 = __builtin_amdgcn_mfma_f32_16x16x32_f16(qa, kb, (f32x4){0, 0, 0, 0}, 0, 0, 0);
            const int rbase = wid * 16 + l4 * 4;
            const int col = nt * 16 + l15;
#pragma unroll
            for (int r = 0; r < 4; ++r)
                sc[nt][r] = scale * s4[r] + bh[(rbase + r) * 64 + col] + mreg[nt][r];
        }
        // ---- softmax fully in registers: one row lives in one 16-lane group
#pragma unroll
        for (int r = 0; r < 4; ++r) {
            float mx = fmaxf(fmaxf(sc[0][r], sc[1][r]), fmaxf(sc[2][r], sc[3][r]));
#pragma unroll
            for (int m = 8; m >= 1; m >>= 1) mx = fmaxf(mx, __shfl_xor(mx, m, 64));
            float p0 = __expf(sc[0][r] - mx);
            float p1 = __expf(sc[1][r] - mx);
            float p2 = __expf(sc[2][r] - mx);
            float p3 = __expf(sc[3][r] - mx);
            float sum = p0 + p1 + p2 + p3;
#pragma unroll
            for (int m = 8; m >= 1; m >>= 1) sum += __shfl_xor(sum, m, 64);
            const float inv = 1.f / sum;
            const int row = wid * 16 + l4 * 4 + r;
            sP[row * 72 +      l15] = (f16)(p0 * inv);
            sP[row * 72 + 16 + l15] = (f16)(p1 * inv);
            sP[row * 72 + 32 + l15] = (f16)(p2 * inv);
            sP[row * 72 + 48 + l15] = (f16)(p3 * inv);
        }
        // ---- O = P V  (wave-private P rows: no barrier needed before reads)
        const f16x8 pa0 = *(const f16x8*)&sP[(wid * 16 + l15) * 72 + l4 * 8];
        const f16x8 pa1 = *(const f16x8*)&sP[(wid * 16 + l15) * 72 + 32 + l4 * 8];
#pragma unroll
        for (int nt = 0; nt < 2; ++nt) {
            f32x4 oacc = {0, 0, 0, 0};
            f16x8 vb0 = *(const f16x8*)&sVt[(nt * 16 + l15) * 72 + l4 * 8];
            f16x8 vb1 = *(const f16x8*)&sVt[(nt * 16 + l15) * 72 + 32 + l4 * 8];
            oacc = __builtin_amdgcn_mfma_f32_16x16x32_f16(pa0, vb0, oacc, 0, 0, 0);
            oacc = __builtin_amdgcn_mfma_f32_16x16x32_f16(pa1, vb1, oacc, 0, 0, 0);
            const int d = nt * 16 + l15;
            if (d < 30) {
                const size_t obase = (size_t)w * 23040 + (size_t)br * 11520 + (size_t)(h * 30 + d);
#pragma unroll
                for (int r = 0; r < 4; ++r) {
                    const int row = wid * 16 + l4 * 4 + r;
                    out_stage[obase + (size_t)row * 180] = (f16)oacc[r];
                }
            }
        }
        __syncthreads();   // protect sQ/sK/sVt for next head
    }
}

// ---------------------------------------------------------------------------
// Kernel B: per window, 8 waves. Gated concat + two final GEMMs via MFMA.
// K streamed in 96-col chunks -> LDS 26624 B (was 51200) so occupancy is
// wave-slot limited, not LDS limited. __launch_bounds__(512,4) guarantees
// >=2 blocks/CU worth of VGPR headroom.
// ---------------------------------------------------------------------------
__global__ __launch_bounds__(512, 4) void final_kernel(
    const float* __restrict__ bpe, const float* __restrict__ bpb,
    const unsigned char* __restrict__ ws, float* __restrict__ d_out)
{
    const int w    = blockIdx.x;
    const int tid  = threadIdx.x;
    const int lane = tid & 63;
    const int l15  = lane & 15;
    const int l4   = lane >> 4;
    const int wid  = __builtin_amdgcn_readfirstlane(tid >> 6);  // 0..7
    const int mt     = wid & 3;
    const int outsel = wid >> 2;   // 0 -> out1 (gate es), 1 -> out2 (gate bs)

    __shared__ f16 sG1[64 * 104];  // o * es, current 96-col K-chunk, 13312 B
    __shared__ f16 sG2[64 * 104];  // o * bs

    const f16* o_stage = (const f16*)(d_out + OUT1_ELEMS);
    const f16* s_stage = (const f16*)d_out;
    const f16* Wt = (const f16*)(ws + (outsel ? WS_WPB_T : WS_WPE_T));

    f32x4 acc[12];
#pragma unroll
    for (int nt = 0; nt < 12; ++nt) acc[nt] = (f32x4){0, 0, 0, 0};

    const size_t sbase = (size_t)w * 23040;
    for (int half = 0; half < 2; ++half) {      // half 0: oe rows, half 1: ob rows
        for (int ch = 0; ch < 2; ++ch) {        // 96-col K-chunks (96..179 + 12 zero-pad)
            __syncthreads();                    // prior A-frag reads done
            for (int idx = tid; idx < 1536; idx += 512) {   // 64 rows * 24 f16x4
                int row = idx / 24, c4i = (idx % 24) * 4;
                int c = ch * 96 + c4i;          // source col 0..191
                f16x4 g1 = {0, 0, 0, 0}, g2 = {0, 0, 0, 0};
                if (c < 180) {
                    f16x4 o4 = *(const f16x4*)&o_stage[sbase + half * 11520 + row * 180 + c];
                    f16x4 e4 = *(const f16x4*)&s_stage[sbase + row * 180 + c];
                    f16x4 b4 = *(const f16x4*)&s_stage[sbase + 11520 + row * 180 + c];
#pragma unroll
                    for (int q = 0; q < 4; ++q) { g1[q] = o4[q] * e4[q]; g2[q] = o4[q] * b4[q]; }
                }
                *(f16x4*)&sG1[row * 104 + c4i] = g1;
                *(f16x4*)&sG2[row * 104 + c4i] = g2;
            }
            __syncthreads();
            const f16* Gs = outsel ? sG2 : sG1;
            f16x8 a[3];
#pragma unroll
            for (int kk = 0; kk < 3; ++kk)
                a[kk] = *(const f16x8*)&Gs[(mt * 16 + l15) * 104 + kk * 32 + l4 * 8];
#pragma unroll
            for (int nt = 0; nt < 12; ++nt) {
#pragma unroll
                for (int kk = 0; kk < 3; ++kk) {
                    f16x8 bf = *(const f16x8*)&Wt[(size_t)(nt * 16 + l15) * 384 + half * 192 + ch * 96 + kk * 32 + l4 * 8];
                    acc[nt] = __builtin_amdgcn_mfma_f32_16x16x32_f16(a[kk], bf, acc[nt], 0, 0, 0);
                }
            }
        }
    }

    // ---- epilogue: bias + f32 store (all staged reads completed before here)
    const float* bias = outsel ? bpb : bpe;
    float* dst = d_out + (outsel ? (size_t)OUT1_ELEMS : (size_t)0) + (size_t)w * 11520;
#pragma unroll
    for (int nt = 0; nt < 12; ++nt) {
        const int col = nt * 16 + l15;
        if (col < 180) {
            const float bv = bias[col];
#pragma unroll
            for (int r = 0; r < 4; ++r) {
                const int row = mt * 16 + l4 * 4 + r;
                dst[(size_t)row * 180 + col] = acc[nt][r] + bv;
            }
        }
    }
}

extern "C" void kernel_launch(void* const* d_in, const int* in_sizes, int n_in,
                              void* d_out, int out_size, void* d_ws, size_t ws_size,
                              hipStream_t stream) {
    const float* e      = (const float*)d_in[0];
    const float* b      = (const float*)d_in[1];
    const float* mask   = (const float*)d_in[2];
    const float* rpb    = (const float*)d_in[3];
    const int*   rpi    = (const int*)  d_in[4];
    const float* Wqkv_e = (const float*)d_in[5];
    const float* bqkv_e = (const float*)d_in[6];
    const float* Wqkv_b = (const float*)d_in[7];
    const float* bqkv_b = (const float*)d_in[8];
    const float* Wpe_s  = (const float*)d_in[9];
    const float* bpe_s  = (const float*)d_in[10];
    const float* Wpb_s  = (const float*)d_in[11];
    const float* bpb_s  = (const float*)d_in[12];
    const float* Wpe    = (const float*)d_in[13];
    const float* bpe    = (const float*)d_in[14];
    const float* Wpb    = (const float*)d_in[15];
    const float* bpb    = (const float*)d_in[16];
    float* out = (float*)d_out;
    unsigned char* ws = (unsigned char*)d_ws;

    pack_kernel<<<dim3(128), dim3(256), 0, stream>>>(
        Wqkv_e, bqkv_e, Wqkv_b, bqkv_b, Wpe_s, bpe_s, Wpb_s, bpb_s,
        Wpe, Wpb, rpb, rpi, ws);
    attn_kernel<<<dim3(NWIN, 2), dim3(256), 0, stream>>>(e, b, mask, ws, out);
    final_kernel<<<dim3(NWIN), dim3(512), 0, stream>>>(bpe, bpb, ws, out);
}

// Round 3
// 2601.938 us; speedup vs baseline: 1.0450x; 1.0450x over previous
//
#include <hip/hip_runtime.h>

#define DIMC 180
#define NHEADS 6
#define NTOK 64
#define NWIN 4096
#define OUT1_ELEMS (NWIN * NTOK * DIMC)  // 47185920 floats per output tensor

typedef _Float16 f16;
typedef _Float16 f16x8 __attribute__((ext_vector_type(8)));
typedef _Float16 f16x4 __attribute__((ext_vector_type(4)));
typedef float    f32x4 __attribute__((ext_vector_type(4)));

// ---- workspace layout (bytes). Total 989184 B (<1 MB).
#define WS_WQKV_E   0         // [576 col][192 k] f16, head-padded cols (h*32+d)
#define WS_WQKV_B   221184
#define WS_WPS_E    442368    // [192 col][192 k] f16, head-padded cols
#define WS_WPS_B    516096
#define WS_WFIN     589824    // [out 2][beta 2][h 6][col 192][d 32] f16 = 294912 B
#define WS_BQKV_E   884736    // [576] f32 head-padded qkv bias
#define WS_BQKV_B   887040
#define WS_BPS_E    889344    // [192] f32 head-padded sigmoid bias
#define WS_BPS_B    890112
#define WS_BIAS     890880    // [6][64][64] f32 = rpb_table[rpi]
// end: 989184

// MFMA fragment conventions (gfx950 v_mfma_f32_16x16x32_f16, HW-verified by
// the passing rounds 1-2):
//   A-frag: lane l holds A[row = l&15][k = (l>>4)*8 + j], j=0..7 (16B contig)
//   B-frag: lane l holds B[k = (l>>4)*8 + j][col = l&15]  (read from W^T)
//   C/D   : lane l, reg r -> row = (l>>4)*4 + r, col = l&15

// ---------------------------------------------------------------------------
// Kernel 0: one-time weight packing (f32 -> f16, pad, transpose) + bias table.
// ---------------------------------------------------------------------------
__global__ __launch_bounds__(256) void pack_kernel(
    const float* __restrict__ Wqkv_e, const float* __restrict__ bqkv_e,
    const float* __restrict__ Wqkv_b, const float* __restrict__ bqkv_b,
    const float* __restrict__ Wpe_s,  const float* __restrict__ bpe_s,
    const float* __restrict__ Wpb_s,  const float* __restrict__ bpb_s,
    const float* __restrict__ Wpe,    const float* __restrict__ Wpb,
    const float* __restrict__ rpb_table, const int* __restrict__ rpi,
    unsigned char* __restrict__ ws)
{
    const int gid  = blockIdx.x * blockDim.x + threadIdx.x;
    const int nthr = gridDim.x * blockDim.x;

    // QKV: packed col c = sec*192 + h*32 + d (d<30 real); k padded to 192.
    f16* wq = (f16*)(ws + WS_WQKV_E);
    for (int idx = gid; idx < 2 * 576 * 192; idx += nthr) {
        int br = idx / (576 * 192), r = idx % (576 * 192);
        int c = r / 192, k = r % 192;
        int s = c / 192, rr = c % 192, h = rr / 32, d = rr % 32;
        const float* W = br ? Wqkv_b : Wqkv_e;
        float v = (d < 30 && k < 180) ? W[k * 540 + s * 180 + h * 30 + d] : 0.f;
        wq[idx] = (f16)v;
    }
    // Sigmoid-gate weights, head-padded cols (h*32+d), transposed, K padded.
    f16* wp = (f16*)(ws + WS_WPS_E);
    for (int idx = gid; idx < 2 * 192 * 192; idx += nthr) {
        int br = idx / (192 * 192), r = idx % (192 * 192);
        int c = r / 192, k = r % 192;
        int h = c / 32, d = c % 32;
        const float* W = br ? Wpb_s : Wpe_s;
        float v = (d < 30 && k < 180) ? W[k * 180 + h * 30 + d] : 0.f;
        wp[idx] = (f16)v;
    }
    // Final-proj weights, per (out, beta, head) 32-row K-blocks, transposed:
    // WFIN[out][beta][h][col][d] = Wp{out}[beta*180 + h*30 + d][col]
    f16* wt = (f16*)(ws + WS_WFIN);
    for (int idx = gid; idx < 2 * 2 * 6 * 192 * 32; idx += nthr) {
        int o  = idx / 73728, r = idx % 73728;     // 2*6*192*32
        int be = r / 36864;  r %= 36864;           // 6*192*32
        int h  = r / 6144;   r %= 6144;            // 192*32
        int col = r / 32, d = r % 32;
        const float* W = o ? Wpb : Wpe;
        float v = (col < 180 && d < 30) ? W[(be * 180 + h * 30 + d) * 180 + col] : 0.f;
        wt[idx] = (f16)v;
    }
    float* bq = (float*)(ws + WS_BQKV_E);
    for (int idx = gid; idx < 2 * 576; idx += nthr) {
        int br = idx / 576, c = idx % 576;
        int s = c / 192, rr = c % 192, h = rr / 32, d = rr % 32;
        const float* B = br ? bqkv_b : bqkv_e;
        bq[idx] = (d < 30) ? B[s * 180 + h * 30 + d] : 0.f;
    }
    float* bp = (float*)(ws + WS_BPS_E);
    for (int idx = gid; idx < 2 * 192; idx += nthr) {
        int br = idx / 192, c = idx % 192;
        int h = c / 32, d = c % 32;
        const float* B = br ? bpb_s : bpe_s;
        bp[idx] = (d < 30) ? B[h * 30 + d] : 0.f;
    }
    float* bh = (float*)(ws + WS_BIAS);
    for (int idx = gid; idx < 6 * 4096; idx += nthr) {
        int h = idx / 4096, ij = idx % 4096;
        bh[idx] = rpb_table[rpi[ij] * NHEADS + h];
    }
}

// ---------------------------------------------------------------------------
// Fused kernel: one block per window, 512 threads (8 waves).
// Waves 0-3: branch e rows 16*mt..; waves 4-7: branch b. Wave g also owns
// out{g+1} accumulation (per-head K=32 blocks over both branches), so the
// staged intermediate never touches HBM.
// LDS 71680 B -> 2 blocks/CU.
// ---------------------------------------------------------------------------
__global__ __launch_bounds__(512, 4) void fused_kernel(
    const float* __restrict__ e, const float* __restrict__ b,
    const float* __restrict__ mask,
    const unsigned char* __restrict__ ws,
    const float* __restrict__ bpe, const float* __restrict__ bpb,
    float* __restrict__ d_out)
{
    const int w    = blockIdx.x;
    const int tid  = threadIdx.x;
    const int lane = tid & 63;
    const int l15  = lane & 15;
    const int l4   = lane >> 4;
    const int wid  = __builtin_amdgcn_readfirstlane(tid >> 6);  // 0..7
    const int mt   = wid & 3;    // row tile (rows mt*16 .. +15)
    const int g    = wid >> 2;   // branch AND out-select

    // LDS: two per-branch arenas of 25600 B. Phase A: sX[beta][64][200].
    // Phase B aliases each arena as sQ[64][40] | sK[64][40] | sVt[32][72] |
    // sP[64][72] (24064 B used). Outside: sO[2][64][40], sGate[2][64][40].
    __shared__ __align__(16) unsigned char smem[71680];
    f16* sXg   = (f16*)(smem + g * 25600);
    f16* sQg   = (f16*)(smem + g * 25600);
    f16* sKg   = (f16*)(smem + g * 25600 + 5120);
    f16* sVtg  = (f16*)(smem + g * 25600 + 10240);
    f16* sPg   = (f16*)(smem + g * 25600 + 14848);
    f16* sO0   = (f16*)(smem + 51200);
    f16* sO1   = (f16*)(smem + 56320);
    f16* sOg   = (f16*)(smem + 51200 + g * 5120);
    f16* sGateg= (f16*)(smem + 61440 + g * 5120);

    const f16*   Wq  = (const f16*)(ws + (g ? WS_WQKV_B : WS_WQKV_E));
    const f16*   Wp  = (const f16*)(ws + (g ? WS_WPS_B  : WS_WPS_E));
    const f16*   Wfin= (const f16*)(ws + WS_WFIN);
    const float* bq  = (const float*)(ws + (g ? WS_BQKV_B : WS_BQKV_E));
    const float* bp  = (const float*)(ws + (g ? WS_BPS_B  : WS_BPS_E));
    const float* bh0 = (const float*)(ws + WS_BIAS);

    // ---- stage X for BOTH branches (f32 -> f16), zero pad cols 180..199
    for (int idx = tid; idx < 2 * 2880; idx += 512) {
        int which = idx / 2880, r = idx % 2880;
        int row = r / 45, c4 = (r % 45) * 4;
        const float* src = (which ? b : e) + (size_t)w * 11520;
        const float4 v = *(const float4*)(src + row * 180 + c4);
        f16x4 hv = { (f16)v.x, (f16)v.y, (f16)v.z, (f16)v.w };
        *(f16x4*)((f16*)(smem + which * 25600) + row * 200 + c4) = hv;
    }
    for (int idx = tid; idx < 2 * 320; idx += 512) {
        int which = idx / 320, r = idx % 320;
        int row = r / 5, c4 = 180 + (r % 5) * 4;
        *(f16x4*)((f16*)(smem + which * 25600) + row * 200 + c4) = (f16x4){0, 0, 0, 0};
    }
    // mask stays exact f32, this thread's 16 S-entries (same for both branches)
    float mreg[4][4];
    {
        const float* mw = mask + (size_t)w * 4096;
        const int rbase = mt * 16 + l4 * 4;
#pragma unroll
        for (int nt = 0; nt < 4; ++nt)
#pragma unroll
            for (int r = 0; r < 4; ++r)
                mreg[nt][r] = mw[(rbase + r) * 64 + nt * 16 + l15];
    }
    __syncthreads();

    // persistent X A-fragments (own branch, own 16 rows) — reused by all GEMMs
    f16x8 a[6];
#pragma unroll
    for (int kk = 0; kk < 6; ++kk)
        a[kk] = *(const f16x8*)&sXg[(mt * 16 + l15) * 200 + kk * 32 + l4 * 8];
    __syncthreads();   // sX dead; arenas become sQ/sK/sVt/sP

    // persistent final-output accumulators (row tile mt, out index g)
    f32x4 acc[12];
#pragma unroll
    for (int nt = 0; nt < 12; ++nt) acc[nt] = (f32x4){0, 0, 0, 0};

    const float scale = 0.18257418583505536f;  // 30^-0.5

    for (int h = 0; h < NHEADS; ++h) {
        // ---- QKV projection for head h (own branch, own rows)
#pragma unroll
        for (int sec = 0; sec < 3; ++sec) {
#pragma unroll
            for (int nt = 0; nt < 2; ++nt) {
                const int colp = sec * 192 + h * 32 + nt * 16;
                f32x4 qacc = {0, 0, 0, 0};
#pragma unroll
                for (int kk = 0; kk < 6; ++kk) {
                    f16x8 bf = *(const f16x8*)&Wq[(size_t)(colp + l15) * 192 + kk * 32 + l4 * 8];
                    qacc = __builtin_amdgcn_mfma_f32_16x16x32_f16(a[kk], bf, qacc, 0, 0, 0);
                }
                const float bv = bq[colp + l15];
                const int d = nt * 16 + l15;          // 0..31 (30,31 are zero-pad)
                if (sec == 2) {
                    f16x4 vv;
#pragma unroll
                    for (int r = 0; r < 4; ++r) vv[r] = (f16)(qacc[r] + bv);
                    *(f16x4*)&sVtg[d * 72 + mt * 16 + l4 * 4] = vv;   // V transposed
                } else {
                    f16* dst = sec ? sKg : sQg;
#pragma unroll
                    for (int r = 0; r < 4; ++r)
                        dst[(mt * 16 + l4 * 4 + r) * 40 + d] = (f16)(qacc[r] + bv);
                }
            }
        }
        // ---- sigmoid gate for head h cols (own branch, own rows)
#pragma unroll
        for (int nt = 0; nt < 2; ++nt) {
            const int colp = h * 32 + nt * 16;
            f32x4 gacc = {0, 0, 0, 0};
#pragma unroll
            for (int kk = 0; kk < 6; ++kk) {
                f16x8 bf = *(const f16x8*)&Wp[(size_t)(colp + l15) * 192 + kk * 32 + l4 * 8];
                gacc = __builtin_amdgcn_mfma_f32_16x16x32_f16(a[kk], bf, gacc, 0, 0, 0);
            }
            const float bv = bp[colp + l15];
            const int d = nt * 16 + l15;
#pragma unroll
            for (int r = 0; r < 4; ++r) {
                float s = 1.f / (1.f + __expf(-(gacc[r] + bv)));
                sGateg[(mt * 16 + l4 * 4 + r) * 40 + d] = (f16)s;
            }
        }
        __syncthreads();   // B1: Q/K/Vt/Gate ready

        // ---- S = scale*Q K^T + bias + mask; softmax in registers
        const float* bh = bh0 + h * 4096;
        const f16x8 qa = *(const f16x8*)&sQg[(mt * 16 + l15) * 40 + l4 * 8];
        float sc[4][4];
#pragma unroll
        for (int nt = 0; nt < 4; ++nt) {
            f16x8 kb = *(const f16x8*)&sKg[(nt * 16 + l15) * 40 + l4 * 8];
            f32x4 s4 = __builtin_amdgcn_mfma_f32_16x16x32_f16(qa, kb, (f32x4){0, 0, 0, 0}, 0, 0, 0);
            const int rbase = mt * 16 + l4 * 4;
            const int col = nt * 16 + l15;
#pragma unroll
            for (int r = 0; r < 4; ++r)
                sc[nt][r] = scale * s4[r] + bh[(rbase + r) * 64 + col] + mreg[nt][r];
        }
#pragma unroll
        for (int r = 0; r < 4; ++r) {
            float mx = fmaxf(fmaxf(sc[0][r], sc[1][r]), fmaxf(sc[2][r], sc[3][r]));
#pragma unroll
            for (int m = 8; m >= 1; m >>= 1) mx = fmaxf(mx, __shfl_xor(mx, m, 64));
            float p0 = __expf(sc[0][r] - mx);
            float p1 = __expf(sc[1][r] - mx);
            float p2 = __expf(sc[2][r] - mx);
            float p3 = __expf(sc[3][r] - mx);
            float sum = p0 + p1 + p2 + p3;
#pragma unroll
            for (int m = 8; m >= 1; m >>= 1) sum += __shfl_xor(sum, m, 64);
            const float inv = 1.f / sum;
            const int row = mt * 16 + l4 * 4 + r;
            sPg[row * 72 +      l15] = (f16)(p0 * inv);
            sPg[row * 72 + 16 + l15] = (f16)(p1 * inv);
            sPg[row * 72 + 32 + l15] = (f16)(p2 * inv);
            sPg[row * 72 + 48 + l15] = (f16)(p3 * inv);
        }
        // ---- O-tile = P V (wave-private P rows; sVt ready since B1)
        const f16x8 pa0 = *(const f16x8*)&sPg[(mt * 16 + l15) * 72 + l4 * 8];
        const f16x8 pa1 = *(const f16x8*)&sPg[(mt * 16 + l15) * 72 + 32 + l4 * 8];
#pragma unroll
        for (int nt = 0; nt < 2; ++nt) {
            f32x4 oacc = {0, 0, 0, 0};
            f16x8 vb0 = *(const f16x8*)&sVtg[(nt * 16 + l15) * 72 + l4 * 8];
            f16x8 vb1 = *(const f16x8*)&sVtg[(nt * 16 + l15) * 72 + 32 + l4 * 8];
            oacc = __builtin_amdgcn_mfma_f32_16x16x32_f16(pa0, vb0, oacc, 0, 0, 0);
            oacc = __builtin_amdgcn_mfma_f32_16x16x32_f16(pa1, vb1, oacc, 0, 0, 0);
            const int d = nt * 16 + l15;
#pragma unroll
            for (int r = 0; r < 4; ++r)
                sOg[(mt * 16 + l4 * 4 + r) * 40 + d] = (f16)oacc[r];
        }
        __syncthreads();   // B2: sO (both branches) + sGate ready

        // ---- per-head final accumulation: out{g}: A = O_beta * gate_g (elemwise)
#pragma unroll
        for (int be = 0; be < 2; ++be) {
            const f16* sOb = be ? sO1 : sO0;
            f16x8 ov = *(const f16x8*)&sOb[(mt * 16 + l15) * 40 + l4 * 8];
            f16x8 gv = *(const f16x8*)&sGateg[(mt * 16 + l15) * 40 + l4 * 8];
            f16x8 Af = ov * gv;
            const f16* wb = Wfin + (size_t)((g * 2 + be) * 6 + h) * 6144;  // [col192][d32]
#pragma unroll
            for (int nt = 0; nt < 12; ++nt) {
                f16x8 bf = *(const f16x8*)&wb[(nt * 16 + l15) * 32 + l4 * 8];
                acc[nt] = __builtin_amdgcn_mfma_f32_16x16x32_f16(Af, bf, acc[nt], 0, 0, 0);
            }
        }
        __syncthreads();   // B3: final reads done; next head may overwrite
    }

    // ---- epilogue: bias + coalesced f32 store (out1 for g=0, out2 for g=1)
    const float* bias = g ? bpb : bpe;
    float* dst = d_out + (g ? (size_t)OUT1_ELEMS : (size_t)0) + (size_t)w * 11520;
#pragma unroll
    for (int nt = 0; nt < 12; ++nt) {
        const int col = nt * 16 + l15;
        if (col < 180) {
            const float bv = bias[col];
#pragma unroll
            for (int r = 0; r < 4; ++r) {
                const int row = mt * 16 + l4 * 4 + r;
                dst[(size_t)row * 180 + col] = acc[nt][r] + bv;
            }
        }
    }
}

extern "C" void kernel_launch(void* const* d_in, const int* in_sizes, int n_in,
                              void* d_out, int out_size, void* d_ws, size_t ws_size,
                              hipStream_t stream) {
    const float* e      = (const float*)d_in[0];
    const float* b      = (const float*)d_in[1];
    const float* mask   = (const float*)d_in[2];
    const float* rpb    = (const float*)d_in[3];
    const int*   rpi    = (const int*)  d_in[4];
    const float* Wqkv_e = (const float*)d_in[5];
    const float* bqkv_e = (const float*)d_in[6];
    const float* Wqkv_b = (const float*)d_in[7];
    const float* bqkv_b = (const float*)d_in[8];
    const float* Wpe_s  = (const float*)d_in[9];
    const float* bpe_s  = (const float*)d_in[10];
    const float* Wpb_s  = (const float*)d_in[11];
    const float* bpb_s  = (const float*)d_in[12];
    const float* Wpe    = (const float*)d_in[13];
    const float* bpe    = (const float*)d_in[14];
    const float* Wpb    = (const float*)d_in[15];
    const float* bpb    = (const float*)d_in[16];
    float* out = (float*)d_out;
    unsigned char* ws = (unsigned char*)d_ws;

    pack_kernel<<<dim3(128), dim3(256), 0, stream>>>(
        Wqkv_e, bqkv_e, Wqkv_b, bqkv_b, Wpe_s, bpe_s, Wpb_s, bpb_s,
        Wpe, Wpb, rpb, rpi, ws);
    fused_kernel<<<dim3(NWIN), dim3(512), 0, stream>>>(
        e, b, mask, ws, bpe, bpb, out);
}